// Round 5
// baseline (295.933 us; speedup 1.0000x reference)
//
#include <hip/hip_runtime.h>
#include <hip/hip_bf16.h>

// Native vector type for nontemporal builtins.
typedef float vf4 __attribute__((ext_vector_type(4)));

// Phase 0: init last_idx to -1.
__global__ void k_init_last(int4* __restrict__ last_idx4, int n4) {
    int stride = gridDim.x * blockDim.x;
    for (int i = blockIdx.x * blockDim.x + threadIdx.x; i < n4; i += stride) {
        last_idx4[i] = make_int4(-1, -1, -1, -1);
    }
}

// Phase 1: per-node last event index via atomicMax.
__global__ void k_last_idx(const int* __restrict__ node_ids,
                           int* __restrict__ last_idx, int E) {
    int i = blockIdx.x * blockDim.x + threadIdx.x;
    if (i < E) {
        atomicMax(&last_idx[node_ids[i]], i);
    }
}

// Phase 2 (inverted): iterate EVENTS; the winning event (the node's last)
// copies its row. msg reads become monotonic-with-gaps (DRAM row-buffer
// friendly); out_msg writes become random but drain through L2's large
// reorder window. times[i] is now a STREAMING read (vs random gather).
// 8 threads per event, 4x16B each.
__global__ void k_scatter(const vf4* __restrict__ msg,
                          const int* __restrict__ node_ids,
                          const int* __restrict__ last_idx,
                          const float* __restrict__ times,
                          vf4* __restrict__ out_msg,
                          float* __restrict__ out_valid,
                          float* __restrict__ out_times, int E) {
    int t = blockIdx.x * blockDim.x + threadIdx.x;
    int ev = t >> 3;
    int q = t & 7;
    if (ev >= E) return;
    int nid = node_ids[ev];
    int li = last_idx[nid];          // random 4B, mostly L2-resident (4MB table)
    if (li != ev) return;            // not the last event for this node
    size_t ib = (size_t)ev * 32 + q;
    size_t ob = (size_t)nid * 32 + q;
    vf4 v0 = __builtin_nontemporal_load(&msg[ib]);
    vf4 v1 = __builtin_nontemporal_load(&msg[ib + 8]);
    vf4 v2 = __builtin_nontemporal_load(&msg[ib + 16]);
    vf4 v3 = __builtin_nontemporal_load(&msg[ib + 24]);
    __builtin_nontemporal_store(v0, &out_msg[ob]);
    __builtin_nontemporal_store(v1, &out_msg[ob + 8]);
    __builtin_nontemporal_store(v2, &out_msg[ob + 16]);
    __builtin_nontemporal_store(v3, &out_msg[ob + 24]);
    if (q == 0) {
        out_valid[nid] = 1.0f;
        out_times[nid] = times[ev];  // streaming read of times
    }
}

// Phase 3: invalid nodes -> zero row, valid=0, times=0. Disjoint from the
// winners' nodes, so order vs k_scatter doesn't matter (both after phase 1).
__global__ void k_finish(const int* __restrict__ last_idx,
                         vf4* __restrict__ out_msg,
                         float* __restrict__ out_valid,
                         float* __restrict__ out_times, int N) {
    int t = blockIdx.x * blockDim.x + threadIdx.x;
    int node = t >> 3;
    int q = t & 7;
    if (node >= N) return;
    int li = last_idx[node];
    if (li >= 0) return;
    size_t ob = (size_t)node * 32 + q;
    vf4 z = (vf4)0.0f;
    __builtin_nontemporal_store(z, &out_msg[ob]);
    __builtin_nontemporal_store(z, &out_msg[ob + 8]);
    __builtin_nontemporal_store(z, &out_msg[ob + 16]);
    __builtin_nontemporal_store(z, &out_msg[ob + 24]);
    if (q == 0) {
        out_valid[node] = 0.0f;
        out_times[node] = 0.0f;
    }
}

extern "C" void kernel_launch(void* const* d_in, const int* in_sizes, int n_in,
                              void* d_out, int out_size, void* d_ws, size_t ws_size,
                              hipStream_t stream) {
    const int*   node_ids = (const int*)d_in[0];
    const float* msg      = (const float*)d_in[1];
    const float* times    = (const float*)d_in[2];
    const int E = in_sizes[0];
    const int N = out_size / 130;   // out = valid[N] + msg[N*128] + times[N]

    float* out_valid = (float*)d_out;
    float* out_msg   = (float*)d_out + N;
    float* out_times = (float*)d_out + N + (size_t)N * 128;

    int* last_idx = (int*)d_ws;     // N ints (4 MB)

    const int B = 256;

    k_init_last<<<2048, B, 0, stream>>>((int4*)last_idx, N / 4);

    k_last_idx<<<(E + B - 1) / B, B, 0, stream>>>(node_ids, last_idx, E);

    long long ts = (long long)E * 8;
    k_scatter<<<(int)((ts + B - 1) / B), B, 0, stream>>>(
        (const vf4*)msg, node_ids, last_idx, times,
        (vf4*)out_msg, out_valid, out_times, E);

    long long tf = (long long)N * 8;
    k_finish<<<(int)((tf + B - 1) / B), B, 0, stream>>>(
        last_idx, (vf4*)out_msg, out_valid, out_times, N);
}